// Round 1
// baseline (228.761 us; speedup 1.0000x reference)
//
#include <hip/hip_runtime.h>
#include <stdint.h>

#define NPAT 4096
#define DIM  256
#define KTOT 1024   // 4 modalities * 256 concatenated
#define EPSV 1e-8f
#define BT 128      // tile (M and N)
#define BK 32       // K per iteration

typedef float  f32x4  __attribute__((ext_vector_type(4)));
typedef __bf16 bf16x8 __attribute__((ext_vector_type(8)));

// ---- workspace layout (bytes) ----
// [0..256): float scalars: [0]=sim_sum, [1]=cox_num, [2]=cox_den
#define WS_EXPH_OFF 256
#define WS_DVAL_OFF (WS_EXPH_OFF + 4*NPAT)      // float4[NPAT]
#define WS_MVEC_OFF (WS_DVAL_OFF + 16*NPAT)     // float4[NPAT]
#define WS_XN_OFF   (WS_MVEC_OFF + 16*NPAT)     // __bf16[NPAT*KTOT] = 8 MB

__device__ __forceinline__ void gl_lds16(const __bf16* g, __bf16* l) {
  __builtin_amdgcn_global_load_lds(
      (const __attribute__((address_space(1))) void*)g,
      (__attribute__((address_space(3))) void*)l, 16, 0, 0);
}

__device__ __forceinline__ float decode_margin(const int* pm) {
  int v = *pm;
  if (v > -16777216 && v < 16777216) return (float)v;  // stored as int
  return __int_as_float(v);                            // stored as float bits
}

// ---------- prep: norms, miss flags, normalized bf16 rows, exp(h) ----------
__global__ __launch_bounds__(256) void prep_kernel(
    const float* __restrict__ eb0, const float* __restrict__ eb1,
    const float* __restrict__ eb2, const float* __restrict__ eb3,
    const float* __restrict__ h,
    __bf16* __restrict__ Xn, float4* __restrict__ dval,
    float4* __restrict__ mvec, float* __restrict__ exph)
{
  const int i   = blockIdx.x;
  const int tid = threadIdx.x;
  const int lane = tid & 63, wv = tid >> 6;
  __shared__ float red[4];
  __shared__ int   missf;
  const float* ebs[4] = {eb0, eb1, eb2, eb3};
  float dv[4], mv[4];

#pragma unroll
  for (int m = 0; m < 4; ++m) {
    __syncthreads();                              // guard shared reuse
    const float x  = ebs[m][(size_t)i * DIM + tid];
    const float x0 = ebs[m][(size_t)i * DIM];
    float s = x * x;
#pragma unroll
    for (int o = 32; o; o >>= 1) s += __shfl_down(s, o, 64);
    if (tid == 0) missf = 1;
    if (lane == 0) red[wv] = s;
    __syncthreads();
    if (x != x0) missf = 0;                       // benign race (all write 0)
    __syncthreads();
    const float ss  = red[0] + red[1] + red[2] + red[3];
    const int miss  = missf;
    const float nrm = sqrtf(ss);
    const float den = fmaxf(nrm, EPSV);
    const float diag = (nrm * nrm) / (den * den); // matches reference formula
    const float invden = 1.0f / den;
    Xn[(size_t)i * KTOT + m * DIM + tid] = miss ? (__bf16)0.0f : (__bf16)(x * invden);
    dv[m] = miss ? 0.0f : diag;
    mv[m] = miss ? 0.0f : 1.0f;
  }
  if (tid == 0) {
    dval[i] = make_float4(dv[0], dv[1], dv[2], dv[3]);
    mvec[i] = make_float4(mv[0], mv[1], mv[2], mv[3]);
    exph[i] = expf(h[i]);
  }
}

// ---------- fused similarity GEMM + epilogue reduction ----------
__global__ __launch_bounds__(256) void sim_gemm_kernel(
    const __bf16* __restrict__ Xn, const float4* __restrict__ dval,
    const float4* __restrict__ mvec, const int* __restrict__ pmargin,
    float* __restrict__ sim_acc)
{
  __shared__ __bf16 lA[BT * BK];
  __shared__ __bf16 lB[BT * BK];
  __shared__ float  eRD[BT][4];
  __shared__ float  eCM[BT][4];
  __shared__ float  wred[4];

  const int bi = blockIdx.y, bj = blockIdx.x;
  const int tid = threadIdx.x;
  const int lane = tid & 63, wv = tid >> 6;
  const int wi = wv >> 1, wj = wv & 1;
  const int rs = tid >> 2, seg = tid & 3;          // staging: 4 lanes/row

  const __bf16* gA = Xn + (size_t)(bi * BT + rs) * KTOT + seg * 8;
  const __bf16* gB = Xn + (size_t)(bj * BT + rs) * KTOT + seg * 8;
  __bf16* lAp = &lA[rs * BK + seg * 8];            // == lA + tid*8 elems (lane*16B)
  __bf16* lBp = &lB[rs * BK + seg * 8];

  f32x4 acc[4][4] = {};

  const int mrow = lane & 15, kg = lane >> 4;
  const int aoff = (wi * 64 + mrow) * BK + kg * 8;
  const int boff = (wj * 64 + mrow) * BK + kg * 8;

  for (int k0 = 0; k0 < KTOT; k0 += BK) {
    __syncthreads();
    gl_lds16(gA + k0,             lAp);
    gl_lds16(gA + k0 + 64 * KTOT, lAp + 64 * BK);
    gl_lds16(gB + k0,             lBp);
    gl_lds16(gB + k0 + 64 * KTOT, lBp + 64 * BK);
    __syncthreads();                               // drains vmcnt before barrier

    bf16x8 af[4], bfr[4];
#pragma unroll
    for (int mi = 0; mi < 4; ++mi) af[mi]  = *(const bf16x8*)&lA[aoff + mi * 16 * BK];
#pragma unroll
    for (int mj = 0; mj < 4; ++mj) bfr[mj] = *(const bf16x8*)&lB[boff + mj * 16 * BK];
#pragma unroll
    for (int mi = 0; mi < 4; ++mi)
#pragma unroll
      for (int mj = 0; mj < 4; ++mj)
        acc[mi][mj] = __builtin_amdgcn_mfma_f32_16x16x32_bf16(
            af[mi], bfr[mj], acc[mi][mj], 0, 0, 0);
  }

  // epilogue: stage per-row dval (for i) and per-col mvec (for j)
  __syncthreads();
  if (tid < BT) *(float4*)&eRD[tid][0]      = dval[bi * BT + tid];
  else          *(float4*)&eCM[tid - BT][0] = mvec[bj * BT + (tid - BT)];
  __syncthreads();

  const float margin = decode_margin(pmargin);
  float local = 0.0f;
  const int rq = (lane >> 4) * 4;                  // C/D: row=(lane>>4)*4+reg
  const int cc = lane & 15;                        //      col=lane&15
#pragma unroll
  for (int mi = 0; mi < 4; ++mi) {
#pragma unroll
    for (int mj = 0; mj < 4; ++mj) {
      const int jl = wj * 64 + mj * 16 + cc;
      const float4 cm = *(const float4*)&eCM[jl][0];
      const int jg = bj * BT + jl;
#pragma unroll
      for (int r = 0; r < 4; ++r) {
        const int il = wi * 64 + mi * 16 + rq + r;
        const float4 rd = *(const float4*)&eRD[il][0];
        const float own = rd.x * cm.x + rd.y * cm.y + rd.z * cm.z + rd.w * cm.w;
        float v = fmaxf(margin - acc[mi][mj][r] + own, 0.0f);
        const int ig = bi * BT + il;
        local += (ig == jg) ? 0.0f : v;
      }
    }
  }
#pragma unroll
  for (int o = 32; o; o >>= 1) local += __shfl_down(local, o, 64);
  if (lane == 0) wred[wv] = local;
  __syncthreads();
  if (tid == 0) atomicAdd(sim_acc, wred[0] + wred[1] + wred[2] + wred[3]);
}

// ---------- Cox negative partial log-likelihood ----------
__global__ __launch_bounds__(256) void cox_kernel(
    const float* __restrict__ h, const int* __restrict__ t,
    const int* __restrict__ e, const float* __restrict__ exph,
    float* __restrict__ num, float* __restrict__ den)
{
  const int i = blockIdx.x;
  const int tid = threadIdx.x;
  const int ti = t[i];
  const int ti2 = ti * ti;                  // max 3649^2 < 2^31
  float s = 0.0f;
  for (int j = tid; j < NPAT; j += 256)
    s += (t[j] * ti >= ti2) ? exph[j] : 0.0f;
  const int lane = tid & 63, wv = tid >> 6;
#pragma unroll
  for (int o = 32; o; o >>= 1) s += __shfl_down(s, o, 64);
  __shared__ float red[4];
  if (lane == 0) red[wv] = s;
  __syncthreads();
  if (tid == 0) {
    const float denom = red[0] + red[1] + red[2] + red[3];
    const float ei = (float)e[i];
    if (ei != 0.0f) atomicAdd(num, ei * (h[i] - logf(denom)));
    atomicAdd(den, ei);
  }
}

__global__ void finalize_kernel(const float* __restrict__ scal, float* __restrict__ out) {
  out[0] = scal[0] - scal[1] / scal[2];    // sim + (-num/den)
}

extern "C" void kernel_launch(void* const* d_in, const int* in_sizes, int n_in,
                              void* d_out, int out_size, void* d_ws, size_t ws_size,
                              hipStream_t stream) {
  const float* h   = (const float*)d_in[0];
  const int*   t   = (const int*)  d_in[1];
  const int*   e   = (const int*)  d_in[2];
  const float* eb0 = (const float*)d_in[3];
  const float* eb1 = (const float*)d_in[4];
  const float* eb2 = (const float*)d_in[5];
  const float* eb3 = (const float*)d_in[6];
  const int*   pm  = (const int*)  d_in[7];

  char*   ws   = (char*)d_ws;
  float*  scal = (float*)ws;
  float*  exph = (float*)(ws + WS_EXPH_OFF);
  float4* dval = (float4*)(ws + WS_DVAL_OFF);
  float4* mvec = (float4*)(ws + WS_MVEC_OFF);
  __bf16* Xn   = (__bf16*)(ws + WS_XN_OFF);

  hipMemsetAsync(d_ws, 0, 256, stream);   // zero accumulators (ws is re-poisoned)
  prep_kernel<<<NPAT, 256, 0, stream>>>(eb0, eb1, eb2, eb3, h, Xn, dval, mvec, exph);
  sim_gemm_kernel<<<dim3(NPAT / BT, NPAT / BT), 256, 0, stream>>>(Xn, dval, mvec, pm, &scal[0]);
  cox_kernel<<<NPAT, 256, 0, stream>>>(h, t, e, exph, &scal[1], &scal[2]);
  finalize_kernel<<<1, 1, 0, stream>>>(scal, (float*)d_out);
}

// Round 2
// 147.919 us; speedup vs baseline: 1.5465x; 1.5465x over previous
//
#include <hip/hip_runtime.h>
#include <stdint.h>

#define NPAT 4096
#define DIM  256
#define KTOT 1024   // 4 modalities * 256 concatenated
#define EPSV 1e-8f
#define BT 128      // tile (M and N)
#define BK 32       // K per iteration
#define NBINS 4096  // time bins (t < 3650), padded to 4096

typedef float  f32x4  __attribute__((ext_vector_type(4)));
typedef __bf16 bf16x8 __attribute__((ext_vector_type(8)));

// ---- workspace layout (bytes) ----
// [0..256): float scalars: [0]=sim_sum, [1]=cox_num, [2]=cox_den
#define WS_BINS_OFF 256                          // float[NBINS] exph-histogram -> suffix sums
#define WS_DVAL_OFF (WS_BINS_OFF + 4*NBINS)      // float4[NPAT]
#define WS_MVEC_OFF (WS_DVAL_OFF + 16*NPAT)      // float4[NPAT]
#define WS_XN_OFF   (WS_MVEC_OFF + 16*NPAT)      // __bf16[NPAT*KTOT] = 8 MB

__device__ __forceinline__ void gl_lds16(const __bf16* g, __bf16* l) {
  __builtin_amdgcn_global_load_lds(
      (const __attribute__((address_space(1))) void*)g,
      (__attribute__((address_space(3))) void*)l, 16, 0, 0);
}

__device__ __forceinline__ float decode_margin(const int* pm) {
  int v = *pm;
  if (v > -16777216 && v < 16777216) return (float)v;  // stored as int
  return __int_as_float(v);                            // stored as float bits
}

// ---------- prep: norms, miss flags, normalized bf16 rows, exph histogram ----------
__global__ __launch_bounds__(256) void prep_kernel(
    const float* __restrict__ eb0, const float* __restrict__ eb1,
    const float* __restrict__ eb2, const float* __restrict__ eb3,
    const float* __restrict__ h, const int* __restrict__ t,
    __bf16* __restrict__ Xn, float4* __restrict__ dval,
    float4* __restrict__ mvec, float* __restrict__ bins)
{
  const int i   = blockIdx.x;
  const int tid = threadIdx.x;
  const int lane = tid & 63, wv = tid >> 6;
  __shared__ float red[4];
  __shared__ int   missf;
  const float* ebs[4] = {eb0, eb1, eb2, eb3};
  float dv[4], mv[4];

#pragma unroll
  for (int m = 0; m < 4; ++m) {
    __syncthreads();                              // guard shared reuse
    const float x  = ebs[m][(size_t)i * DIM + tid];
    const float x0 = ebs[m][(size_t)i * DIM];
    float s = x * x;
#pragma unroll
    for (int o = 32; o; o >>= 1) s += __shfl_down(s, o, 64);
    if (tid == 0) missf = 1;
    if (lane == 0) red[wv] = s;
    __syncthreads();
    if (x != x0) missf = 0;                       // benign race (all write 0)
    __syncthreads();
    const float ss  = red[0] + red[1] + red[2] + red[3];
    const int miss  = missf;
    const float nrm = sqrtf(ss);
    const float den = fmaxf(nrm, EPSV);
    const float diag = (nrm * nrm) / (den * den); // matches reference formula
    const float invden = 1.0f / den;
    Xn[(size_t)i * KTOT + m * DIM + tid] = miss ? (__bf16)0.0f : (__bf16)(x * invden);
    dv[m] = miss ? 0.0f : diag;
    mv[m] = miss ? 0.0f : 1.0f;
  }
  if (tid == 0) {
    dval[i] = make_float4(dv[0], dv[1], dv[2], dv[3]);
    mvec[i] = make_float4(mv[0], mv[1], mv[2], mv[3]);
    atomicAdd(&bins[t[i]], expf(h[i]));           // exph histogram by time
  }
}

// ---------- suffix-sum the histogram in place: bins[b] <- sum_{v>=b} bins[v] ----------
__global__ __launch_bounds__(1024) void scan_kernel(float* __restrict__ bins)
{
  __shared__ float p[1024];
  const int tid = threadIdx.x;
  float4 b = ((float4*)bins)[tid];
  const float part = b.x + b.y + b.z + b.w;
  p[tid] = part;
  __syncthreads();
  for (int off = 1; off < 1024; off <<= 1) {      // inclusive suffix scan
    const float v = p[tid];
    const float a = (tid + off < 1024) ? p[tid + off] : 0.0f;
    __syncthreads();
    p[tid] = v + a;
    __syncthreads();
  }
  float run = p[tid] - part;                      // exclusive suffix (chunks above)
  float4 S;
  run += b.w; S.w = run;
  run += b.z; S.z = run;
  run += b.y; S.y = run;
  run += b.x; S.x = run;
  ((float4*)bins)[tid] = S;
}

// ---------- Cox numerator/denominator via suffix-sum lookup ----------
__global__ __launch_bounds__(256) void cox_final_kernel(
    const float* __restrict__ h, const int* __restrict__ t,
    const int* __restrict__ e, const float* __restrict__ S,
    float* __restrict__ num, float* __restrict__ den)
{
  const int j = blockIdx.x * 256 + threadIdx.x;
  const float ej = (float)e[j];
  float nloc = (ej != 0.0f) ? ej * (h[j] - logf(S[t[j]])) : 0.0f;
  float dloc = ej;
  const int lane = threadIdx.x & 63, wv = threadIdx.x >> 6;
#pragma unroll
  for (int o = 32; o; o >>= 1) {
    nloc += __shfl_down(nloc, o, 64);
    dloc += __shfl_down(dloc, o, 64);
  }
  __shared__ float rn[4], rd[4];
  if (lane == 0) { rn[wv] = nloc; rd[wv] = dloc; }
  __syncthreads();
  if (threadIdx.x == 0) {
    atomicAdd(num, rn[0] + rn[1] + rn[2] + rn[3]);
    atomicAdd(den, rd[0] + rd[1] + rd[2] + rd[3]);
  }
}

// ---------- fused similarity GEMM + epilogue (symmetric: bi <= bj only) ----------
__global__ __launch_bounds__(256) void sim_gemm_kernel(
    const __bf16* __restrict__ Xn, const float4* __restrict__ dval,
    const float4* __restrict__ mvec, const int* __restrict__ pmargin,
    float* __restrict__ sim_acc)
{
  const int bi = blockIdx.y, bj = blockIdx.x;
  if (bj < bi) return;                             // symmetric: upper triangle only

  __shared__ __bf16 lA[BT * BK];
  __shared__ __bf16 lB[BT * BK];
  __shared__ float  eRDi[BT][4], eCMi[BT][4];      // dval/mvec for row tile (bi)
  __shared__ float  eRDj[BT][4], eCMj[BT][4];      // dval/mvec for col tile (bj)
  __shared__ float  wred[4];

  const int tid = threadIdx.x;
  const int lane = tid & 63, wv = tid >> 6;
  const int wi = wv >> 1, wj = wv & 1;
  const int rs = tid >> 2, seg = tid & 3;          // staging: 4 lanes/row

  const __bf16* gA = Xn + (size_t)(bi * BT + rs) * KTOT + seg * 8;
  const __bf16* gB = Xn + (size_t)(bj * BT + rs) * KTOT + seg * 8;
  __bf16* lAp = &lA[rs * BK + seg * 8];            // == lA + tid*8 elems (lane*16B)
  __bf16* lBp = &lB[rs * BK + seg * 8];

  f32x4 acc[4][4] = {};

  const int mrow = lane & 15, kg = lane >> 4;
  const int aoff = (wi * 64 + mrow) * BK + kg * 8;
  const int boff = (wj * 64 + mrow) * BK + kg * 8;

  for (int k0 = 0; k0 < KTOT; k0 += BK) {
    __syncthreads();
    gl_lds16(gA + k0,             lAp);
    gl_lds16(gA + k0 + 64 * KTOT, lAp + 64 * BK);
    gl_lds16(gB + k0,             lBp);
    gl_lds16(gB + k0 + 64 * KTOT, lBp + 64 * BK);
    __syncthreads();                               // drains vmcnt before barrier

    bf16x8 af[4], bfr[4];
#pragma unroll
    for (int mi = 0; mi < 4; ++mi) af[mi]  = *(const bf16x8*)&lA[aoff + mi * 16 * BK];
#pragma unroll
    for (int mj = 0; mj < 4; ++mj) bfr[mj] = *(const bf16x8*)&lB[boff + mj * 16 * BK];
#pragma unroll
    for (int mi = 0; mi < 4; ++mi)
#pragma unroll
      for (int mj = 0; mj < 4; ++mj)
        acc[mi][mj] = __builtin_amdgcn_mfma_f32_16x16x32_bf16(
            af[mi], bfr[mj], acc[mi][mj], 0, 0, 0);
  }

  // epilogue: stage dval/mvec for both tiles
  __syncthreads();
  if (tid < BT) {
    *(float4*)&eRDi[tid][0] = dval[bi * BT + tid];
    *(float4*)&eCMi[tid][0] = mvec[bi * BT + tid];
  } else {
    const int s = tid - BT;
    *(float4*)&eRDj[s][0] = dval[bj * BT + s];
    *(float4*)&eCMj[s][0] = mvec[bj * BT + s];
  }
  __syncthreads();

  const float margin = decode_margin(pmargin);
  const bool isDiag = (bi == bj);
  float local = 0.0f;
  const int rq = (lane >> 4) * 4;                  // C/D: row=(lane>>4)*4+reg
  const int cc = lane & 15;                        //      col=lane&15
#pragma unroll
  for (int mi = 0; mi < 4; ++mi) {
#pragma unroll
    for (int mj = 0; mj < 4; ++mj) {
      const int jl = wj * 64 + mj * 16 + cc;
      const float4 cmj = *(const float4*)&eCMj[jl][0];
      const float4 rdj = *(const float4*)&eRDj[jl][0];
#pragma unroll
      for (int r = 0; r < 4; ++r) {
        const int il = wi * 64 + mi * 16 + rq + r;
        const float4 rdi = *(const float4*)&eRDi[il][0];
        const float s = acc[mi][mj][r];
        const float own_ij = rdi.x * cmj.x + rdi.y * cmj.y + rdi.z * cmj.z + rdi.w * cmj.w;
        const float v1 = fmaxf(margin - s + own_ij, 0.0f);
        local += (isDiag && il == jl) ? 0.0f : v1;
        if (!isDiag) {                             // transposed pair (j,i)
          const float4 cmi = *(const float4*)&eCMi[il][0];
          const float own_ji = rdj.x * cmi.x + rdj.y * cmi.y + rdj.z * cmi.z + rdj.w * cmi.w;
          local += fmaxf(margin - s + own_ji, 0.0f);
        }
      }
    }
  }
#pragma unroll
  for (int o = 32; o; o >>= 1) local += __shfl_down(local, o, 64);
  if (lane == 0) wred[wv] = local;
  __syncthreads();
  if (tid == 0) atomicAdd(sim_acc, wred[0] + wred[1] + wred[2] + wred[3]);
}

__global__ void finalize_kernel(const float* __restrict__ scal, float* __restrict__ out) {
  out[0] = scal[0] - scal[1] / scal[2];    // sim + (-num/den)
}

extern "C" void kernel_launch(void* const* d_in, const int* in_sizes, int n_in,
                              void* d_out, int out_size, void* d_ws, size_t ws_size,
                              hipStream_t stream) {
  const float* h   = (const float*)d_in[0];
  const int*   t   = (const int*)  d_in[1];
  const int*   e   = (const int*)  d_in[2];
  const float* eb0 = (const float*)d_in[3];
  const float* eb1 = (const float*)d_in[4];
  const float* eb2 = (const float*)d_in[5];
  const float* eb3 = (const float*)d_in[6];
  const int*   pm  = (const int*)  d_in[7];

  char*   ws   = (char*)d_ws;
  float*  scal = (float*)ws;
  float*  bins = (float*)(ws + WS_BINS_OFF);
  float4* dval = (float4*)(ws + WS_DVAL_OFF);
  float4* mvec = (float4*)(ws + WS_MVEC_OFF);
  __bf16* Xn   = (__bf16*)(ws + WS_XN_OFF);

  hipMemsetAsync(d_ws, 0, WS_BINS_OFF + 4 * NBINS, stream);  // scalars + bins
  prep_kernel<<<NPAT, 256, 0, stream>>>(eb0, eb1, eb2, eb3, h, t, Xn, dval, mvec, bins);
  scan_kernel<<<1, 1024, 0, stream>>>(bins);
  cox_final_kernel<<<NPAT / 256, 256, 0, stream>>>(h, t, e, bins, &scal[1], &scal[2]);
  sim_gemm_kernel<<<dim3(NPAT / BT, NPAT / BT), 256, 0, stream>>>(Xn, dval, mvec, pm, &scal[0]);
  finalize_kernel<<<1, 1, 0, stream>>>(scal, (float*)d_out);
}

// Round 3
// 140.503 us; speedup vs baseline: 1.6282x; 1.0528x over previous
//
#include <hip/hip_runtime.h>
#include <stdint.h>

#define NPAT 4096
#define DIM  256
#define KTOT 1024   // 4 modalities * 256 concatenated
#define EPSV 1e-8f
#define BT  128     // tile (M and N)
#define BK2 64      // K per staging iteration (2 MFMA k-steps of 32)
#define NT  (NPAT / BT)            // 32 tiles per dim
#define NBLK (NT * (NT + 1) / 2)   // 528 upper-triangle blocks
#define NBINS 4096  // time bins (t < 3650), padded

typedef float  f32x4  __attribute__((ext_vector_type(4)));
typedef __bf16 bf16x8 __attribute__((ext_vector_type(8)));
typedef __bf16 bf16x4 __attribute__((ext_vector_type(4)));

// ---- workspace layout (bytes) ----
// [0..256): float scalars: [0]=sim_sum
#define WS_DVAL_OFF 256                          // float[NPAT*4] (float4/patient)
#define WS_MVEC_OFF (WS_DVAL_OFF + 16*NPAT)      // float[NPAT*4]
#define WS_XN_OFF   (WS_MVEC_OFF + 16*NPAT)      // __bf16[NPAT*KTOT] = 8 MB

__device__ __forceinline__ void gl_lds16(const __bf16* g, __bf16* l) {
  __builtin_amdgcn_global_load_lds(
      (const __attribute__((address_space(1))) void*)g,
      (__attribute__((address_space(3))) void*)l, 16, 0, 0);
}

__device__ __forceinline__ float decode_margin(const int* pm) {
  int v = *pm;
  if (v > -16777216 && v < 16777216) return (float)v;  // stored as int
  return __int_as_float(v);                            // stored as float bits
}

// ---------- prep: wave-per-(patient,modality), no barriers ----------
__global__ __launch_bounds__(256) void prep_kernel(
    const float4* __restrict__ eb0, const float4* __restrict__ eb1,
    const float4* __restrict__ eb2, const float4* __restrict__ eb3,
    __bf16* __restrict__ Xn, float* __restrict__ dval_f,
    float* __restrict__ mvec_f)
{
  const int i    = blockIdx.x;
  const int wv   = threadIdx.x >> 6;   // modality
  const int lane = threadIdx.x & 63;
  const float4* ebs[4] = {eb0, eb1, eb2, eb3};
  const float4 v = ebs[wv][i * (DIM / 4) + lane];
  float s = v.x * v.x + v.y * v.y + v.z * v.z + v.w * v.w;
#pragma unroll
  for (int o = 32; o; o >>= 1) s += __shfl_down(s, o, 64);
  s = __shfl(s, 0, 64);
  const float x0 = __shfl(v.x, 0, 64);
  const bool eq = (v.x == x0) && (v.y == x0) && (v.z == x0) && (v.w == x0);
  const bool miss = (__ballot(eq) == ~0ull);
  const float nrm = sqrtf(s);
  const float den = fmaxf(nrm, EPSV);
  const float inv = miss ? 0.0f : (1.0f / den);
  bf16x4 o4;
  o4[0] = (__bf16)(v.x * inv); o4[1] = (__bf16)(v.y * inv);
  o4[2] = (__bf16)(v.z * inv); o4[3] = (__bf16)(v.w * inv);
  *(bf16x4*)&Xn[(size_t)i * KTOT + wv * DIM + lane * 4] = o4;
  if (lane == 0) {
    const float diag = (nrm * nrm) / (den * den);
    dval_f[i * 4 + wv] = miss ? 0.0f : diag;
    mvec_f[i * 4 + wv] = miss ? 0.0f : 1.0f;
  }
}

// ---------- fused similarity GEMM + epilogue (upper triangle, 1D grid) ----------
__global__ __launch_bounds__(256) void sim_gemm_kernel(
    const __bf16* __restrict__ Xn, const float4* __restrict__ dval,
    const float4* __restrict__ mvec, const int* __restrict__ pmargin,
    float* __restrict__ sim_acc)
{
  __shared__ __bf16 lA[BT * BK2];
  __shared__ __bf16 lB[BT * BK2];
  __shared__ float  eRDi[BT][4], eCMi[BT][4], eRDj[BT][4], eCMj[BT][4];
  __shared__ float  wred[4];

  // linear -> (bi, bj) upper triangle, row-major
  const int L = blockIdx.x;
  int bi = (int)((2 * NT + 1 - sqrtf((float)((2 * NT + 1) * (2 * NT + 1)) - 8.0f * L)) * 0.5f);
  if (bi < 0) bi = 0;
  if (bi > NT - 1) bi = NT - 1;
  while (bi > 0 && bi * NT - bi * (bi - 1) / 2 > L) --bi;
  while ((bi + 1) * NT - (bi + 1) * bi / 2 <= L) ++bi;
  const int bj = bi + (L - (bi * NT - bi * (bi - 1) / 2));

  const int tid = threadIdx.x;
  const int lane = tid & 63, wv = tid >> 6;
  const int wi = wv >> 1, wj = wv & 1;

  // staging: thread tid stages 16B; physical (row,chunk)=(c*32+tid>>3, tid&7);
  // logical chunk s8 = phys ^ (row&7)  (XOR swizzle kills bank conflicts)
  const int rhi = tid >> 3;
  const int s8  = (tid & 7) ^ ((tid >> 3) & 7);
  const __bf16* gA = Xn + (size_t)(bi * BT) * KTOT;
  const __bf16* gB = Xn + (size_t)(bj * BT) * KTOT;

  f32x4 acc[4][4] = {};
  const int mrow = lane & 15, kg = lane >> 4, x7 = lane & 7;
  const int rbaseA = wi * 64 + mrow;
  const int rbaseB = wj * 64 + mrow;

  for (int k0 = 0; k0 < KTOT; k0 += BK2) {
    __syncthreads();
#pragma unroll
    for (int c = 0; c < 4; ++c) {
      const size_t ro = (size_t)(c * 32 + rhi) * KTOT + k0 + s8 * 8;
      gl_lds16(gA + ro, &lA[c * 2048 + tid * 8]);
      gl_lds16(gB + ro, &lB[c * 2048 + tid * 8]);
    }
    __syncthreads();   // compiler drains vmcnt before s_barrier
#pragma unroll
    for (int t = 0; t < 2; ++t) {
      bf16x8 af[4], bfr[4];
      const int co = ((t * 4 + kg) ^ x7) * 8;
#pragma unroll
      for (int mi = 0; mi < 4; ++mi) af[mi]  = *(const bf16x8*)&lA[(rbaseA + mi * 16) * BK2 + co];
#pragma unroll
      for (int mj = 0; mj < 4; ++mj) bfr[mj] = *(const bf16x8*)&lB[(rbaseB + mj * 16) * BK2 + co];
#pragma unroll
      for (int mi = 0; mi < 4; ++mi)
#pragma unroll
        for (int mj = 0; mj < 4; ++mj)
          acc[mi][mj] = __builtin_amdgcn_mfma_f32_16x16x32_bf16(
              af[mi], bfr[mj], acc[mi][mj], 0, 0, 0);
    }
  }

  // epilogue: stage dval/mvec for both tiles
  __syncthreads();
  if (tid < BT) {
    *(float4*)&eRDi[tid][0] = dval[bi * BT + tid];
    *(float4*)&eCMi[tid][0] = mvec[bi * BT + tid];
  } else {
    const int s = tid - BT;
    *(float4*)&eRDj[s][0] = dval[bj * BT + s];
    *(float4*)&eCMj[s][0] = mvec[bj * BT + s];
  }
  __syncthreads();

  const float margin = decode_margin(pmargin);
  const bool isDiag = (bi == bj);
  float local = 0.0f;
  const int rq = (lane >> 4) * 4;                  // C/D: row=(lane>>4)*4+reg
  const int cc = lane & 15;                        //      col=lane&15
#pragma unroll
  for (int mi = 0; mi < 4; ++mi) {
#pragma unroll
    for (int mj = 0; mj < 4; ++mj) {
      const int jl = wj * 64 + mj * 16 + cc;
      const float4 cmj = *(const float4*)&eCMj[jl][0];
      const float4 rdj = *(const float4*)&eRDj[jl][0];
#pragma unroll
      for (int r = 0; r < 4; ++r) {
        const int il = wi * 64 + mi * 16 + rq + r;
        const float4 rdi = *(const float4*)&eRDi[il][0];
        const float sv = acc[mi][mj][r];
        const float own_ij = rdi.x * cmj.x + rdi.y * cmj.y + rdi.z * cmj.z + rdi.w * cmj.w;
        const float v1 = fmaxf(margin - sv + own_ij, 0.0f);
        local += (isDiag && il == jl) ? 0.0f : v1;
        if (!isDiag) {                             // transposed pair (j,i)
          const float4 cmi = *(const float4*)&eCMi[il][0];
          const float own_ji = rdj.x * cmi.x + rdj.y * cmi.y + rdj.z * cmi.z + rdj.w * cmi.w;
          local += fmaxf(margin - sv + own_ji, 0.0f);
        }
      }
    }
  }
#pragma unroll
  for (int o = 32; o; o >>= 1) local += __shfl_down(local, o, 64);
  if (lane == 0) wred[wv] = local;
  __syncthreads();
  if (tid == 0) atomicAdd(sim_acc, wred[0] + wred[1] + wred[2] + wred[3]);
}

// ---------- Cox: histogram + suffix-scan + NPLL + finalize, one block ----------
__global__ __launch_bounds__(1024) void cox_kernel(
    const float* __restrict__ h, const int* __restrict__ t,
    const int* __restrict__ e, const float* __restrict__ scal,
    float* __restrict__ out)
{
  __shared__ float bins[NBINS];
  __shared__ float p[1024];
  __shared__ float rn[16], rd[16];
  const int tid = threadIdx.x;
#pragma unroll
  for (int k = 0; k < 4; ++k) bins[tid + k * 1024] = 0.0f;
  __syncthreads();
#pragma unroll
  for (int k = 0; k < 4; ++k) {
    const int i = tid + k * 1024;
    atomicAdd(&bins[t[i]], expf(h[i]));
  }
  __syncthreads();
  // suffix scan: bins[b] <- sum_{v>=b} bins[v]; thread owns bins[4t..4t+3]
  const float b0 = bins[4 * tid], b1 = bins[4 * tid + 1];
  const float b2 = bins[4 * tid + 2], b3 = bins[4 * tid + 3];
  const float part = b0 + b1 + b2 + b3;
  p[tid] = part;
  __syncthreads();
  for (int off = 1; off < 1024; off <<= 1) {
    const float v = p[tid];
    const float a = (tid + off < 1024) ? p[tid + off] : 0.0f;
    __syncthreads();
    p[tid] = v + a;
    __syncthreads();
  }
  const float above = p[tid] - part;
  const float s3 = above + b3, s2 = s3 + b2, s1 = s2 + b1, s0 = s1 + b0;
  bins[4 * tid] = s0; bins[4 * tid + 1] = s1;
  bins[4 * tid + 2] = s2; bins[4 * tid + 3] = s3;
  __syncthreads();
  float nloc = 0.0f, dloc = 0.0f;
#pragma unroll
  for (int k = 0; k < 4; ++k) {
    const int i = tid + k * 1024;
    const float ei = (float)e[i];
    if (ei != 0.0f) { nloc += ei * (h[i] - logf(bins[t[i]])); dloc += ei; }
  }
  const int lane = tid & 63, w = tid >> 6;
#pragma unroll
  for (int o = 32; o; o >>= 1) {
    nloc += __shfl_down(nloc, o, 64);
    dloc += __shfl_down(dloc, o, 64);
  }
  if (lane == 0) { rn[w] = nloc; rd[w] = dloc; }
  __syncthreads();
  if (tid == 0) {
    float n = 0.0f, d = 0.0f;
#pragma unroll
    for (int k = 0; k < 16; ++k) { n += rn[k]; d += rd[k]; }
    out[0] = scal[0] - n / d;   // sim + cox
  }
}

extern "C" void kernel_launch(void* const* d_in, const int* in_sizes, int n_in,
                              void* d_out, int out_size, void* d_ws, size_t ws_size,
                              hipStream_t stream) {
  const float* h   = (const float*)d_in[0];
  const int*   t   = (const int*)  d_in[1];
  const int*   e   = (const int*)  d_in[2];
  const float4* eb0 = (const float4*)d_in[3];
  const float4* eb1 = (const float4*)d_in[4];
  const float4* eb2 = (const float4*)d_in[5];
  const float4* eb3 = (const float4*)d_in[6];
  const int*   pm  = (const int*)  d_in[7];

  char*   ws   = (char*)d_ws;
  float*  scal = (float*)ws;
  float*  dvf  = (float*)(ws + WS_DVAL_OFF);
  float*  mvf  = (float*)(ws + WS_MVEC_OFF);
  __bf16* Xn   = (__bf16*)(ws + WS_XN_OFF);

  hipMemsetAsync(d_ws, 0, 256, stream);   // zero sim accumulator
  prep_kernel<<<NPAT, 256, 0, stream>>>(eb0, eb1, eb2, eb3, Xn, dvf, mvf);
  sim_gemm_kernel<<<NBLK, 256, 0, stream>>>(Xn, (const float4*)dvf, (const float4*)mvf, pm, &scal[0]);
  cox_kernel<<<1, 1024, 0, stream>>>(h, t, e, scal, (float*)d_out);
}

// Round 4
// 133.647 us; speedup vs baseline: 1.7117x; 1.0513x over previous
//
#include <hip/hip_runtime.h>
#include <stdint.h>

#define NPAT 4096
#define DIM  256
#define KB   1024       // bytes per patient row: 4 modalities * 256 fp8
#define EPSV 1e-8f
#define BT   64         // tile (M and N)
#define BKB  128        // K-bytes per staging iter = 4 MFMA k-steps of 32
#define NT   (NPAT / BT)            // 64 tiles per dim
#define NBLK (NT * (NT + 1) / 2)    // 2080 upper-triangle blocks
#define NBINS 4096

typedef float f32x4 __attribute__((ext_vector_type(4)));

// ---- workspace layout (bytes) ----
// [0..256): float scalars: [0]=sim_sum
#define WS_DVAL_OFF 256                          // float4[NPAT]
#define WS_MVEC_OFF (WS_DVAL_OFF + 16*NPAT)      // float4[NPAT]
#define WS_XN_OFF   (WS_MVEC_OFF + 16*NPAT)      // uint8[NPAT*KB] = 4 MB (L2-resident!)

__device__ __forceinline__ void gl_lds16(const uint8_t* g, uint8_t* l) {
  __builtin_amdgcn_global_load_lds(
      (const __attribute__((address_space(1))) void*)g,
      (__attribute__((address_space(3))) void*)l, 16, 0, 0);
}

__device__ __forceinline__ float decode_margin(const int* pm) {
  int v = *pm;
  if (v > -16777216 && v < 16777216) return (float)v;  // stored as int
  return __int_as_float(v);                            // stored as float bits
}

// ---------- prep: wave-per-(patient,modality); fp8 quantize; zero accumulator ----------
__global__ __launch_bounds__(256) void prep_kernel(
    const float4* __restrict__ eb0, const float4* __restrict__ eb1,
    const float4* __restrict__ eb2, const float4* __restrict__ eb3,
    uint8_t* __restrict__ Xn, float* __restrict__ dval_f,
    float* __restrict__ mvec_f, float* __restrict__ scal)
{
  const int i    = blockIdx.x;
  const int wv   = threadIdx.x >> 6;   // modality
  const int lane = threadIdx.x & 63;
  const float4* ebs[4] = {eb0, eb1, eb2, eb3};
  const float4 v = ebs[wv][i * (DIM / 4) + lane];
  float s = v.x * v.x + v.y * v.y + v.z * v.z + v.w * v.w;
#pragma unroll
  for (int o = 32; o; o >>= 1) s += __shfl_down(s, o, 64);
  s = __shfl(s, 0, 64);
  const float x0 = __shfl(v.x, 0, 64);
  const bool eq = (v.x == x0) && (v.y == x0) && (v.z == x0) && (v.w == x0);
  const bool miss = (__ballot(eq) == ~0ull);
  const float nrm = sqrtf(s);
  const float den = fmaxf(nrm, EPSV);
  const float inv = miss ? 0.0f : (1.0f / den);
  int p = 0;
  p = __builtin_amdgcn_cvt_pk_fp8_f32(v.x * inv, v.y * inv, p, false);
  p = __builtin_amdgcn_cvt_pk_fp8_f32(v.z * inv, v.w * inv, p, true);
  *(int*)&Xn[(size_t)i * KB + wv * DIM + lane * 4] = p;
  if (lane == 0) {
    const float diag = (nrm * nrm) / (den * den);
    dval_f[i * 4 + wv] = miss ? 0.0f : diag;
    mvec_f[i * 4 + wv] = miss ? 0.0f : 1.0f;
  }
  if (i == 0 && threadIdx.x == 0) scal[0] = 0.0f;  // zero sim accumulator (ws is poisoned)
}

// ---------- fused similarity GEMM + epilogue (upper triangle, fp8, BT=64) ----------
__global__ __launch_bounds__(256, 8) void sim_gemm_kernel(
    const uint8_t* __restrict__ Xn, const float4* __restrict__ dval,
    const float4* __restrict__ mvec, const int* __restrict__ pmargin,
    float* __restrict__ sim_acc)
{
  __shared__ __align__(16) uint8_t lA[BT * BKB];   // 8 KB
  __shared__ __align__(16) uint8_t lB[BT * BKB];   // 8 KB
  __shared__ float wred[4];

  // linear -> (bi, bj) upper triangle, row-major
  const int L = blockIdx.x;
  int bi = (int)((2 * NT + 1 - sqrtf((float)((2 * NT + 1) * (2 * NT + 1)) - 8.0f * L)) * 0.5f);
  if (bi < 0) bi = 0;
  if (bi > NT - 1) bi = NT - 1;
  while (bi > 0 && bi * NT - bi * (bi - 1) / 2 > L) --bi;
  while ((bi + 1) * NT - (bi + 1) * bi / 2 <= L) ++bi;
  const int bj = bi + (L - (bi * NT - bi * (bi - 1) / 2));

  const int tid = threadIdx.x;
  const int lane = tid & 63, wvv = tid >> 6;
  const int wi = wvv >> 1, wj = wvv & 1;

  // staging: thread stages 16 B (one chunk-pair). LDS dest must be tid-contiguous
  // (wave-uniform base + lane*16). XOR swizzle: slot s of row r holds global pair
  // p = s ^ (r&7); 8 B halves unswizzled -> 16 B global stays contiguous.
  const int r0 = tid >> 3;            // rows 0..31 (q=0); q=1 adds 32 (same r&7)
  const int p16 = ((tid & 7) ^ (r0 & 7)) * 16;
  const uint8_t* gA = Xn + (size_t)(bi * BT) * KB;
  const uint8_t* gB = Xn + (size_t)(bj * BT) * KB;

  f32x4 acc[2][2] = {};
  const int mrow = lane & 15, kg = lane >> 4;
  const int rA0 = wi * 32 + mrow;
  const int rB0 = wj * 32 + mrow;
  const int swA7 = (rA0 & 7), swB7 = (rB0 & 7);

  for (int k0 = 0; k0 < KB; k0 += BKB) {
    __syncthreads();
    gl_lds16(gA + (size_t)r0 * KB        + k0 + p16, &lA[tid * 16]);
    gl_lds16(gA + (size_t)(r0 + 32) * KB + k0 + p16, &lA[4096 + tid * 16]);
    gl_lds16(gB + (size_t)r0 * KB        + k0 + p16, &lB[tid * 16]);
    gl_lds16(gB + (size_t)(r0 + 32) * KB + k0 + p16, &lB[4096 + tid * 16]);
    __syncthreads();   // compiler drains vmcnt before s_barrier
#pragma unroll
    for (int t = 0; t < 4; ++t) {
      const int c = t * 4 + kg;                   // chunk (8 B) within 128-B window
      const int half = (c & 1) * 8, sw = c >> 1;
      const int oA = ((sw ^ swA7) * 16) + half;
      const int oB = ((sw ^ swB7) * 16) + half;
      const long a0 = *(const long*)&lA[rA0 * BKB + oA];
      const long a1 = *(const long*)&lA[(rA0 + 16) * BKB + oA];
      const long b0 = *(const long*)&lB[rB0 * BKB + oB];
      const long b1 = *(const long*)&lB[(rB0 + 16) * BKB + oB];
      acc[0][0] = __builtin_amdgcn_mfma_f32_16x16x32_fp8_fp8(a0, b0, acc[0][0], 0, 0, 0);
      acc[0][1] = __builtin_amdgcn_mfma_f32_16x16x32_fp8_fp8(a0, b1, acc[0][1], 0, 0, 0);
      acc[1][0] = __builtin_amdgcn_mfma_f32_16x16x32_fp8_fp8(a1, b0, acc[1][0], 0, 0, 0);
      acc[1][1] = __builtin_amdgcn_mfma_f32_16x16x32_fp8_fp8(a1, b1, acc[1][1], 0, 0, 0);
    }
  }

  // epilogue: alias dval/mvec staging onto lA (done with tile reads)
  __syncthreads();
  float4* eRDi = (float4*)lA;
  float4* eCMi = (float4*)lA + 64;
  float4* eRDj = (float4*)lA + 128;
  float4* eCMj = (float4*)lA + 192;
  if (tid < 64) {
    eRDi[tid] = dval[bi * BT + tid];
    eCMi[tid] = mvec[bi * BT + tid];
  } else if (tid < 128) {
    const int s = tid - 64;
    eRDj[s] = dval[bj * BT + s];
    eCMj[s] = mvec[bj * BT + s];
  }
  __syncthreads();

  const float margin = decode_margin(pmargin);
  const bool isDiag = (bi == bj);
  float local = 0.0f;
  const int rq = (lane >> 4) * 4;                  // C/D: row=(lane>>4)*4+reg
  const int cc = lane & 15;                        //      col=lane&15
#pragma unroll
  for (int mi = 0; mi < 2; ++mi) {
#pragma unroll
    for (int mj = 0; mj < 2; ++mj) {
      const int jl = wj * 32 + mj * 16 + cc;
      const float4 cmj = eCMj[jl];
      const float4 rdj = eRDj[jl];
#pragma unroll
      for (int r = 0; r < 4; ++r) {
        const int il = wi * 32 + mi * 16 + rq + r;
        const float4 rdi = eRDi[il];
        const float sv = acc[mi][mj][r];
        const float own_ij = rdi.x * cmj.x + rdi.y * cmj.y + rdi.z * cmj.z + rdi.w * cmj.w;
        const float v1 = fmaxf(margin - sv + own_ij, 0.0f);
        local += (isDiag && il == jl) ? 0.0f : v1;
        if (!isDiag) {                             // transposed pair (j,i)
          const float4 cmi = eCMi[il];
          const float own_ji = rdj.x * cmi.x + rdj.y * cmi.y + rdj.z * cmi.z + rdj.w * cmi.w;
          local += fmaxf(margin - sv + own_ji, 0.0f);
        }
      }
    }
  }
#pragma unroll
  for (int o = 32; o; o >>= 1) local += __shfl_down(local, o, 64);
  if (lane == 0) wred[wvv] = local;
  __syncthreads();
  if (tid == 0) atomicAdd(sim_acc, wred[0] + wred[1] + wred[2] + wred[3]);
}

// ---------- Cox: histogram + suffix-scan + NPLL + finalize, one block ----------
__global__ __launch_bounds__(1024) void cox_kernel(
    const float* __restrict__ h, const int* __restrict__ t,
    const int* __restrict__ e, const float* __restrict__ scal,
    float* __restrict__ out)
{
  __shared__ float bins[NBINS];
  __shared__ float p[1024];
  __shared__ float rn[16], rd[16];
  const int tid = threadIdx.x;
#pragma unroll
  for (int k = 0; k < 4; ++k) bins[tid + k * 1024] = 0.0f;
  __syncthreads();
#pragma unroll
  for (int k = 0; k < 4; ++k) {
    const int i = tid + k * 1024;
    atomicAdd(&bins[t[i]], expf(h[i]));
  }
  __syncthreads();
  // suffix scan: bins[b] <- sum_{v>=b} bins[v]; thread owns bins[4t..4t+3]
  const float b0 = bins[4 * tid], b1 = bins[4 * tid + 1];
  const float b2 = bins[4 * tid + 2], b3 = bins[4 * tid + 3];
  const float part = b0 + b1 + b2 + b3;
  p[tid] = part;
  __syncthreads();
  for (int off = 1; off < 1024; off <<= 1) {
    const float v = p[tid];
    const float a = (tid + off < 1024) ? p[tid + off] : 0.0f;
    __syncthreads();
    p[tid] = v + a;
    __syncthreads();
  }
  const float above = p[tid] - part;
  const float s3 = above + b3, s2 = s3 + b2, s1 = s2 + b1, s0 = s1 + b0;
  bins[4 * tid] = s0; bins[4 * tid + 1] = s1;
  bins[4 * tid + 2] = s2; bins[4 * tid + 3] = s3;
  __syncthreads();
  float nloc = 0.0f, dloc = 0.0f;
#pragma unroll
  for (int k = 0; k < 4; ++k) {
    const int i = tid + k * 1024;
    const float ei = (float)e[i];
    if (ei != 0.0f) { nloc += ei * (h[i] - logf(bins[t[i]])); dloc += ei; }
  }
  const int lane = tid & 63, w = tid >> 6;
#pragma unroll
  for (int o = 32; o; o >>= 1) {
    nloc += __shfl_down(nloc, o, 64);
    dloc += __shfl_down(dloc, o, 64);
  }
  if (lane == 0) { rn[w] = nloc; rd[w] = dloc; }
  __syncthreads();
  if (tid == 0) {
    float n = 0.0f, d = 0.0f;
#pragma unroll
    for (int k = 0; k < 16; ++k) { n += rn[k]; d += rd[k]; }
    out[0] = scal[0] - n / d;   // sim + cox
  }
}

extern "C" void kernel_launch(void* const* d_in, const int* in_sizes, int n_in,
                              void* d_out, int out_size, void* d_ws, size_t ws_size,
                              hipStream_t stream) {
  const float* h    = (const float*)d_in[0];
  const int*   t    = (const int*)  d_in[1];
  const int*   e    = (const int*)  d_in[2];
  const float4* eb0 = (const float4*)d_in[3];
  const float4* eb1 = (const float4*)d_in[4];
  const float4* eb2 = (const float4*)d_in[5];
  const float4* eb3 = (const float4*)d_in[6];
  const int*   pm   = (const int*)  d_in[7];

  char*    ws   = (char*)d_ws;
  float*   scal = (float*)ws;
  float*   dvf  = (float*)(ws + WS_DVAL_OFF);
  float*   mvf  = (float*)(ws + WS_MVEC_OFF);
  uint8_t* Xn   = (uint8_t*)(ws + WS_XN_OFF);

  prep_kernel<<<NPAT, 256, 0, stream>>>(eb0, eb1, eb2, eb3, Xn, dvf, mvf, scal);
  sim_gemm_kernel<<<NBLK, 256, 0, stream>>>(Xn, (const float4*)dvf, (const float4*)mvf, pm, &scal[0]);
  cox_kernel<<<1, 1024, 0, stream>>>(h, t, e, scal, (float*)d_out);
}